// Round 16
// baseline (277.358 us; speedup 1.0000x reference)
//
#include <hip/hip_runtime.h>
#include <hip/hip_fp16.h>
#include <stdint.h>

typedef __bf16 bf16_t;
typedef __attribute__((ext_vector_type(8))) __bf16 bfv8;
typedef __attribute__((ext_vector_type(4))) __bf16 bfv4;
typedef __attribute__((ext_vector_type(4))) float f32x4;

constexpr int BATCH = 2, SEQ = 8192, DIM = 1024, NH = 16, HDIM = 64, FDIM = 256;
constexpr int MROWS = BATCH * SEQ;  // 16384
constexpr int NCHUNK = 32;          // kv s-chunks (256 s each)
constexpr int KV_NIT = (SEQ / NCHUNK) / 32;  // 8 iterations of 32 s
constexpr int KVP_CH = 32 * 256 * 68;        // 557056 halfs per chunk ([bh][f][n])

__device__ __forceinline__ f32x4 mfma_bf16(bfv8 a, bfv8 b, f32x4 c) {
  return __builtin_amdgcn_mfma_f32_16x16x32_bf16(a, b, c, 0, 0, 0);
}

// ---- async global->LDS 16B (LDS dst wave-uniform base + lane*16) ----
__device__ __forceinline__ void gload_lds16(const bf16_t* g, bf16_t* lds) {
  auto const* gp = reinterpret_cast<const __attribute__((address_space(1))) uint32_t*>(
      reinterpret_cast<uintptr_t>(g));
  auto* lp = reinterpret_cast<__attribute__((address_space(3))) uint32_t*>(
      reinterpret_cast<uintptr_t>(lds));
  __builtin_amdgcn_global_load_lds(gp, lp, 16, 0, 0);
}

// ---- stage a 128x64 bf16 tile into LDS (linear [128][64]), xor-swizzled source ----
__device__ __forceinline__ void stage128x64(const bf16_t* g_base, int k0,
                                            bf16_t* lds, int wid, int lane) {
#pragma unroll
  for (int j = 0; j < 4; ++j) {
    int r0 = (wid * 4 + j) * 8;                 // wave-uniform
    int g_row = r0 + (lane >> 3);
    int g_slot = (lane & 7) ^ (g_row & 7);
    const bf16_t* src = g_base + (size_t)g_row * DIM + k0 + g_slot * 8;
    gload_lds16(src, lds + r0 * 64);
  }
}

// ---------------- fused fp32 -> bf16 converts: X, Wq,Wk,Wv, Wo, Wf ----------------
__global__ __launch_bounds__(256) void cvt_all(const float* __restrict__ X,
                                               const float* __restrict__ Wq,
                                               const float* __restrict__ Wk,
                                               const float* __restrict__ Wv,
                                               const float* __restrict__ Wo,
                                               const float* __restrict__ Wf,
                                               bf16_t* __restrict__ Xb,
                                               bf16_t* __restrict__ W3,
                                               bf16_t* __restrict__ Wob,
                                               bf16_t* __restrict__ Wfb) {
  int i = blockIdx.x * 256 + threadIdx.x;
  const float* src;
  bf16_t* dst;
  int off;
  if (i < 4194304) {
    src = X; dst = Xb; off = i;
  } else {
    int j = i - 4194304;
    if (j < 786432) {
      int seg = j >> 18;
      off = j & 262143;
      src = (seg == 0) ? Wq : ((seg == 1) ? Wk : Wv);
      dst = W3 + (size_t)seg * 1048576;
    } else if (j < 1048576) {
      off = j - 786432; src = Wo; dst = Wob;
    } else {
      off = j - 1048576; src = Wf; dst = Wfb;
    }
  }
  float4 v = reinterpret_cast<const float4*>(src)[off];
  bfv4 o = {(__bf16)v.x, (__bf16)v.y, (__bf16)v.z, (__bf16)v.w};
  reinterpret_cast<bfv4*>(dst)[off] = o;
}

// -------- Q/K/V projection: C = X @ W^T (bf16 out), 2-phase dbuf LDS pipeline --------
// 1-D grid 3072, XCD-aware panel grouping (R14-verified: FETCH 147->90MB).
__global__ __launch_bounds__(256) void gemm_qkv(const bf16_t* __restrict__ A,
                                                const bf16_t* __restrict__ Wall,
                                                bf16_t* __restrict__ Q,
                                                bf16_t* __restrict__ K,
                                                bf16_t* __restrict__ V) {
  __shared__ bf16_t As[2][128 * 64];
  __shared__ bf16_t Bs[2][128 * 64];
  int bid = blockIdx.x;
  int xcd = bid & 7, s = bid >> 3;
  int pair = xcd * 48 + (s >> 3);
  int z = pair >> 7, bx = pair & 127, by = s & 7;
  const bf16_t* Wm = Wall + (size_t)z * (DIM * DIM);
  bf16_t* C = (z == 0) ? Q : ((z == 1) ? K : V);
  int lane = threadIdx.x & 63, wid = threadIdx.x >> 6;
  int lr = lane & 15, lg = lane >> 4;
  int wr = wid >> 1, wc = wid & 1;
  int brow = bx * 128, bcol = by * 128;
  const bf16_t* Ab = A + (size_t)brow * DIM;
  const bf16_t* Bb = Wm + (size_t)bcol * DIM;
  f32x4 acc[4][4] = {};

  stage128x64(Ab, 0, As[0], wid, lane);
  stage128x64(Bb, 0, Bs[0], wid, lane);
  asm volatile("s_waitcnt vmcnt(0)" ::: "memory");
  __builtin_amdgcn_s_barrier();

  auto TILE = [&](const bf16_t* Acur, const bf16_t* Bcur, bf16_t* Anext, bf16_t* Bnext,
                  int knext) __attribute__((always_inline)) {
    if (knext < DIM) {
      stage128x64(Ab, knext, Anext, wid, lane);
      stage128x64(Bb, knext, Bnext, wid, lane);
    }
#pragma unroll
    for (int kk = 0; kk < 2; ++kk) {
      bfv8 af[4], bg[4];
#pragma unroll
      for (int t = 0; t < 4; ++t) {
        int ar = wr * 64 + t * 16 + lr;
        af[t] = *reinterpret_cast<const bfv8*>(&Acur[ar * 64 + (((kk * 4 + lg) ^ (ar & 7)) * 8)]);
        int br = wc * 64 + t * 16 + lr;
        bg[t] = *reinterpret_cast<const bfv8*>(&Bcur[br * 64 + (((kk * 4 + lg) ^ (br & 7)) * 8)]);
      }
#pragma unroll
      for (int i = 0; i < 4; ++i)
#pragma unroll
        for (int j = 0; j < 4; ++j) acc[i][j] = mfma_bf16(af[i], bg[j], acc[i][j]);
    }
    asm volatile("s_waitcnt vmcnt(0)" ::: "memory");
    __builtin_amdgcn_s_barrier();
  };

  for (int ks = 0; ks < DIM / 64; ks += 2) {
    TILE(As[0], Bs[0], As[1], Bs[1], (ks + 1) * 64);
    TILE(As[1], Bs[1], As[0], Bs[0], (ks + 2) * 64);
  }

#pragma unroll
  for (int i = 0; i < 4; ++i) {
    int r = brow + wr * 64 + i * 16 + lg * 4;
#pragma unroll
    for (int j = 0; j < 4; ++j) {
      int c = bcol + wc * 64 + j * 16 + lr;
#pragma unroll
      for (int q = 0; q < 4; ++q) C[(size_t)(r + q) * DIM + c] = (__bf16)acc[i][j][q];
    }
  }
}

// -------- final: d_out = out_pre @ Wo^T (fp32 out), 2-phase dbuf, XCD panel grouping ----
__global__ __launch_bounds__(256) void gemm_final(const bf16_t* __restrict__ A,
                                                  const bf16_t* __restrict__ W,
                                                  float* __restrict__ C) {
  __shared__ bf16_t As[2][128 * 64];
  __shared__ bf16_t Bs[2][128 * 64];
  int bid = blockIdx.x;
  int xcd = bid & 7, s = bid >> 3;
  int bx = xcd * 16 + (s >> 3);
  int by = s & 7;
  int lane = threadIdx.x & 63, wid = threadIdx.x >> 6;
  int lr = lane & 15, lg = lane >> 4;
  int wr = wid >> 1, wc = wid & 1;
  int brow = bx * 128, bcol = by * 128;
  const bf16_t* Ab = A + (size_t)brow * DIM;
  const bf16_t* Bb = W + (size_t)bcol * DIM;
  f32x4 acc[4][4] = {};

  stage128x64(Ab, 0, As[0], wid, lane);
  stage128x64(Bb, 0, Bs[0], wid, lane);
  asm volatile("s_waitcnt vmcnt(0)" ::: "memory");
  __builtin_amdgcn_s_barrier();

  auto TILE = [&](const bf16_t* Acur, const bf16_t* Bcur, bf16_t* Anext, bf16_t* Bnext,
                  int knext) __attribute__((always_inline)) {
    if (knext < DIM) {
      stage128x64(Ab, knext, Anext, wid, lane);
      stage128x64(Bb, knext, Bnext, wid, lane);
    }
#pragma unroll
    for (int kk = 0; kk < 2; ++kk) {
      bfv8 af[4], bg[4];
#pragma unroll
      for (int t = 0; t < 4; ++t) {
        int ar = wr * 64 + t * 16 + lr;
        af[t] = *reinterpret_cast<const bfv8*>(&Acur[ar * 64 + (((kk * 4 + lg) ^ (ar & 7)) * 8)]);
        int br = wc * 64 + t * 16 + lr;
        bg[t] = *reinterpret_cast<const bfv8*>(&Bcur[br * 64 + (((kk * 4 + lg) ^ (br & 7)) * 8)]);
      }
#pragma unroll
      for (int i = 0; i < 4; ++i)
#pragma unroll
        for (int j = 0; j < 4; ++j) acc[i][j] = mfma_bf16(af[i], bg[j], acc[i][j]);
    }
    asm volatile("s_waitcnt vmcnt(0)" ::: "memory");
    __builtin_amdgcn_s_barrier();
  };

  for (int ks = 0; ks < DIM / 64; ks += 2) {
    TILE(As[0], Bs[0], As[1], Bs[1], (ks + 1) * 64);
    TILE(As[1], Bs[1], As[0], Bs[0], (ks + 2) * 64);
  }

#pragma unroll
  for (int i = 0; i < 4; ++i) {
    int r = brow + wr * 64 + i * 16 + lg * 4;
#pragma unroll
    for (int j = 0; j < 4; ++j) {
      int c = bcol + wc * 64 + j * 16 + lr;
#pragma unroll
      for (int q = 0; q < 4; ++q) C[(size_t)(r + q) * DIM + c] = acc[i][j][q];
    }
  }
}

// ------- fused featk+kv v6: in-register kf + per-wave LDS V-transpose; NCHUNK=32 -------
__global__ __launch_bounds__(256, 2) void kv_fused(const bf16_t* __restrict__ Kb,
                                                   const bf16_t* __restrict__ Vb,
                                                   const bf16_t* __restrict__ Wf,
                                                   __half* __restrict__ kv_part) {
  __shared__ bf16_t vt[4][64 * 36];  // per-wave V^T tile [n=64][s=32], stride 36
  int chunk = blockIdx.x, bh = blockIdx.y;
  int b = bh >> 4, h = bh & 15;
  int lane = threadIdx.x & 63, wid = threadIdx.x >> 6;
  int lr = lane & 15, lg = lane >> 4;
  int f0 = wid * 64;
  bfv8 wf[4][2];
#pragma unroll
  for (int ft = 0; ft < 4; ++ft)
#pragma unroll
    for (int kk = 0; kk < 2; ++kk)
      wf[ft][kk] = *reinterpret_cast<const bfv8*>(Wf + (size_t)(f0 + ft * 16 + lr) * HDIM + kk * 32 + lg * 8);
  const bf16_t* Kbase = Kb + (size_t)b * SEQ * DIM + h * HDIM;
  const bf16_t* Vbase = Vb + (size_t)b * SEQ * DIM + h * HDIM;
  int s0 = chunk * (SEQ / NCHUNK);
  bfv8 ones;
#pragma unroll
  for (int j = 0; j < 8; ++j) ones[j] = (lr == 0) ? (__bf16)1.0f : (__bf16)0.0f;

  bfv8 krgA[2][2], krgB[2][2];
#pragma unroll
  for (int st = 0; st < 2; ++st)
#pragma unroll
    for (int kk = 0; kk < 2; ++kk)
      krgA[st][kk] = *reinterpret_cast<const bfv8*>(Kbase + (size_t)(s0 + st * 16 + lr) * DIM + kk * 32 + lg * 8);

  f32x4 acc[4][5] = {};

  auto STEP = [&](int it, bfv8(&krgC)[2][2], bfv8(&krgN)[2][2]) __attribute__((always_inline)) {
    int sb = s0 + it * 32;
    bfv8 vv[4];
#pragma unroll
    for (int rep = 0; rep < 4; ++rep) {
      int idx = rep * 64 + lane;
      vv[rep] = *reinterpret_cast<const bfv8*>(Vbase + (size_t)(sb + (idx >> 3)) * DIM + (idx & 7) * 8);
    }
    if (it + 1 < KV_NIT) {
#pragma unroll
      for (int st = 0; st < 2; ++st)
#pragma unroll
        for (int kk = 0; kk < 2; ++kk)
          krgN[st][kk] = *reinterpret_cast<const bfv8*>(Kbase + (size_t)(sb + 32 + st * 16 + lr) * DIM + kk * 32 + lg * 8);
    }
    f32x4 ckf[2][4] = {};
#pragma unroll
    for (int st = 0; st < 2; ++st)
#pragma unroll
      for (int ft = 0; ft < 4; ++ft)
#pragma unroll
        for (int kk = 0; kk < 2; ++kk) ckf[st][ft] = mfma_bf16(krgC[st][kk], wf[ft][kk], ckf[st][ft]);
#pragma unroll
    for (int rep = 0; rep < 4; ++rep) {
      int idx = rep * 64 + lane;
#pragma unroll
      for (int j = 0; j < 8; ++j) vt[wid][((idx & 7) * 8 + j) * 36 + (idx >> 3)] = vv[rep][j];
    }
    bfv8 af[4];
#pragma unroll
    for (int ft = 0; ft < 4; ++ft)
#pragma unroll
      for (int st = 0; st < 2; ++st)
#pragma unroll
        for (int q = 0; q < 4; ++q) {
          float x = ckf[st][ft][q];
          x = (x > 0.0f) ? (x + 1.0f) : __expf(x);
          af[ft][st * 4 + q] = (__bf16)x;
        }
    bfv8 bg[4];
#pragma unroll
    for (int nt = 0; nt < 4; ++nt) {
      bfv4 lo = *reinterpret_cast<const bfv4*>(&vt[wid][(nt * 16 + lr) * 36 + lg * 4]);
      bfv4 hi = *reinterpret_cast<const bfv4*>(&vt[wid][(nt * 16 + lr) * 36 + 16 + lg * 4]);
#pragma unroll
      for (int e = 0; e < 4; ++e) { bg[nt][e] = lo[e]; bg[nt][4 + e] = hi[e]; }
    }
#pragma unroll
    for (int ft = 0; ft < 4; ++ft) {
#pragma unroll
      for (int nt = 0; nt < 4; ++nt) acc[ft][nt] = mfma_bf16(af[ft], bg[nt], acc[ft][nt]);
      acc[ft][4] = mfma_bf16(af[ft], ones, acc[ft][4]);
    }
  };

  for (int it2 = 0; it2 < KV_NIT; it2 += 2) {
    STEP(it2, krgA, krgB);
    STEP(it2 + 1, krgB, krgA);
  }

  __half* outb = kv_part + ((size_t)chunk * 32 + bh) * (FDIM * 68);
#pragma unroll
  for (int ft = 0; ft < 4; ++ft)
#pragma unroll
    for (int q = 0; q < 4; ++q) {
      int f = f0 + ft * 16 + lg * 4 + q;
#pragma unroll
      for (int nt = 0; nt < 4; ++nt)
        outb[(size_t)f * 68 + nt * 16 + lr] = __float2half(acc[ft][nt][q]);
      if (lr < 4) outb[(size_t)f * 68 + 64 + lr] = __float2half(acc[ft][4][q]);
    }
}

// ------- reduce NCHUNK fp16 partials [bh][f][n] -> kvT bf16 [bh][n=80][f-XOR-swz] -------
__global__ __launch_bounds__(256) void kv_reduce(const __half* __restrict__ part,
                                                 bf16_t* __restrict__ kvT) {
  int i = blockIdx.x * 256 + threadIdx.x;  // grid 2560: 557056 reduce + 98304 zero-fill
  if (i < KVP_CH) {
    int n = i % 68;
    int t = i / 68;  // bh*256 + f
    int f = t & 255, bh = t >> 8;
    float s = 0.0f;
#pragma unroll
    for (int c = 0; c < NCHUNK; ++c) s += __half2float(part[(size_t)c * KVP_CH + i]);
    int fs = ((((f >> 3) ^ (n & 7)) << 3) | (f & 7));
    kvT[((size_t)bh * 80 + n) * FDIM + fs] = (__bf16)s;
  } else {
    int j = i - KVP_CH;  // 32*12*256
    int f = j & 255;
    int t = j >> 8;
    int n = 68 + t % 12, bh = t / 12;
    kvT[((size_t)bh * 80 + n) * FDIM + f] = (__bf16)0.0f;
  }
}

// ------- fused featq+readout, 256 rows/block: stage kvT once, four 64-row sub-tiles ----
// grid (M/256, NH); b = row00>>13 (256-row blocks never straddle batch boundary).
__global__ __launch_bounds__(256) void attn_fused(const bf16_t* __restrict__ Qb,
                                                  const bf16_t* __restrict__ Wf,
                                                  const bf16_t* __restrict__ kvT,
                                                  bf16_t* __restrict__ outp) {
  __shared__ bf16_t qf_lds[64 * 264];
  __shared__ bf16_t kv_lds[80 * 256];
  int rb = blockIdx.x, h = blockIdx.y;
  int row00 = rb * 256;
  int bh = (row00 >> 13) * NH + h;
  int lane = threadIdx.x & 63, wid = threadIdx.x >> 6;
  int lr = lane & 15, lg = lane >> 4;
  int f0 = wid * 64;
  // stage kvT[bh] -> LDS once (linear; swizzle pre-applied in global layout)
  const bf16_t* kvTb = kvT + (size_t)bh * 80 * FDIM;
#pragma unroll
  for (int i = 0; i < 10; ++i) {
    int sbase = wid * 640 + i * 64;
    gload_lds16(kvTb + (size_t)(sbase + lane) * 8, kv_lds + sbase * 8);
  }
  bfv8 wfb[4][2];
#pragma unroll
  for (int t = 0; t < 4; ++t)
#pragma unroll
    for (int kk = 0; kk < 2; ++kk)
      wfb[t][kk] = *reinterpret_cast<const bfv8*>(Wf + (size_t)(f0 + t * 16 + lr) * HDIM + kk * 32 + lg * 8);

#pragma unroll
  for (int sub = 0; sub < 4; ++sub) {
    int row0 = row00 + sub * 64;
    bfv8 qa[4][2];
#pragma unroll
    for (int t = 0; t < 4; ++t)
#pragma unroll
      for (int kk = 0; kk < 2; ++kk)
        qa[t][kk] = *reinterpret_cast<const bfv8*>(Qb + (size_t)(row0 + t * 16 + lr) * DIM + h * HDIM + kk * 32 + lg * 8);
    f32x4 cq[4][4] = {};
#pragma unroll
    for (int rt = 0; rt < 4; ++rt)
#pragma unroll
      for (int ft = 0; ft < 4; ++ft)
#pragma unroll
        for (int kk = 0; kk < 2; ++kk) cq[rt][ft] = mfma_bf16(qa[rt][kk], wfb[ft][kk], cq[rt][ft]);
#pragma unroll
    for (int rt = 0; rt < 4; ++rt)
#pragma unroll
      for (int ft = 0; ft < 4; ++ft)
#pragma unroll
        for (int q = 0; q < 4; ++q) {
          float x = cq[rt][ft][q];
          x = (x > 0.0f) ? (x + 1.0f) : __expf(x);
          qf_lds[(size_t)(rt * 16 + lg * 4 + q) * 264 + f0 + ft * 16 + lr] = (__bf16)x;
        }
    __syncthreads();  // qf visible (sub0 also drains kv staging vmcnt)
    f32x4 acc[5] = {};
#pragma unroll
    for (int ks = 0; ks < 8; ++ks) {
      bfv8 a = *reinterpret_cast<const bfv8*>(&qf_lds[(size_t)(wid * 16 + lr) * 264 + ks * 32 + lg * 8]);
#pragma unroll
      for (int nt = 0; nt < 5; ++nt) {
        bfv8 bg = *reinterpret_cast<const bfv8*>(
            &kv_lds[(size_t)(nt * 16 + lr) * 256 + (((ks * 4 + lg) ^ (lr & 7)) * 8)]);
        acc[nt] = mfma_bf16(a, bg, acc[nt]);
      }
    }
    __syncthreads();  // all waves done reading qf_lds
#pragma unroll
    for (int q = 0; q < 4; ++q) {
      float nrm = __shfl(acc[4][q], (lane & 48)) + 1e-6f;
      int row = wid * 16 + lg * 4 + q;
#pragma unroll
      for (int nt = 0; nt < 4; ++nt)
        qf_lds[(size_t)row * 264 + nt * 16 + lr] = (__bf16)(acc[nt][q] / nrm);
    }
    __syncthreads();
#pragma unroll
    for (int rep = 0; rep < 2; ++rep) {
      int id = rep * 256 + threadIdx.x;
      int row = id >> 3, c8 = id & 7;
      bfv8 v = *reinterpret_cast<const bfv8*>(&qf_lds[(size_t)row * 264 + c8 * 8]);
      *reinterpret_cast<bfv8*>(&outp[(size_t)(row0 + row) * DIM + h * HDIM + c8 * 8]) = v;
    }
    __syncthreads();  // out-tile reads done before next sub overwrites qf_lds
  }
}

extern "C" void kernel_launch(void* const* d_in, const int* in_sizes, int n_in,
                              void* d_out, int out_size, void* d_ws, size_t ws_size,
                              hipStream_t stream) {
  const float* X  = (const float*)d_in[0];
  const float* Wq = (const float*)d_in[1];
  const float* Wk = (const float*)d_in[2];
  const float* Wv = (const float*)d_in[3];
  const float* Wo = (const float*)d_in[4];
  const float* Wf = (const float*)d_in[5];
  float* out = (float*)d_out;
  char* ws = (char*)d_ws;
  const size_t MB = 1ull << 20;
  if (ws_size < 75 * MB) return;

  // arena (75 MB) + d_out (64 MB) as scratch for K/V
  bf16_t* Xb  = (bf16_t*)(ws + 0 * MB);    // 32MB; dead after gemm_qkv
  bf16_t* W3  = (bf16_t*)(ws + 32 * MB);   // 6MB;  dead after gemm_qkv
  bf16_t* Qb  = (bf16_t*)(ws + 38 * MB);   // 32MB; live until attn_fused
  bf16_t* Wob = (bf16_t*)(ws + 70 * MB);   // 2MB;  live until gemm_final
  bf16_t* Wfb = (bf16_t*)(ws + 72 * MB);   // 32KB
  bf16_t* kvT = (bf16_t*)(ws + 73 * MB);   // 1.31MB
  __half* kv_part = (__half*)(ws + 0 * MB);  // 35.7MB fp16 over dead Xb+W3
  bf16_t* outp = (bf16_t*)(ws + 0 * MB);   // 32MB over dead kv_part
  bf16_t* Kb = (bf16_t*)d_out;             // 32MB scratch in d_out
  bf16_t* Vb = Kb + (size_t)MROWS * DIM;   // 32MB scratch in d_out

  cvt_all<<<20496, 256, 0, stream>>>(X, Wq, Wk, Wv, Wo, Wf, Xb, W3, Wob, Wfb);

  gemm_qkv<<<3072, 256, 0, stream>>>(Xb, W3, Qb, Kb, Vb);
  kv_fused<<<dim3(NCHUNK, 32), 256, 0, stream>>>(Kb, Vb, Wfb, kv_part);
  kv_reduce<<<2560, 256, 0, stream>>>(kv_part, kvT);
  attn_fused<<<dim3(64, NH), 256, 0, stream>>>(Qb, Wfb, kvT, outp);
  gemm_final<<<1024, 256, 0, stream>>>(outp, Wob, out);
}

// Round 17
// 270.435 us; speedup vs baseline: 1.0256x; 1.0256x over previous
//
#include <hip/hip_runtime.h>
#include <hip/hip_fp16.h>
#include <stdint.h>

typedef __bf16 bf16_t;
typedef __attribute__((ext_vector_type(8))) __bf16 bfv8;
typedef __attribute__((ext_vector_type(4))) __bf16 bfv4;
typedef __attribute__((ext_vector_type(4))) float f32x4;

constexpr int BATCH = 2, SEQ = 8192, DIM = 1024, NH = 16, HDIM = 64, FDIM = 256;
constexpr int MROWS = BATCH * SEQ;  // 16384
constexpr int NCHUNK = 32;          // kv s-chunks (256 s each)
constexpr int KV_NIT = (SEQ / NCHUNK) / 32;  // 8 iterations of 32 s
constexpr int KVP_CH = 32 * 256 * 68;        // 557056 halfs per chunk ([bh][f][n])

__device__ __forceinline__ f32x4 mfma_bf16(bfv8 a, bfv8 b, f32x4 c) {
  return __builtin_amdgcn_mfma_f32_16x16x32_bf16(a, b, c, 0, 0, 0);
}

// ---- async global->LDS 16B (LDS dst wave-uniform base + lane*16) ----
__device__ __forceinline__ void gload_lds16(const bf16_t* g, bf16_t* lds) {
  auto const* gp = reinterpret_cast<const __attribute__((address_space(1))) uint32_t*>(
      reinterpret_cast<uintptr_t>(g));
  auto* lp = reinterpret_cast<__attribute__((address_space(3))) uint32_t*>(
      reinterpret_cast<uintptr_t>(lds));
  __builtin_amdgcn_global_load_lds(gp, lp, 16, 0, 0);
}

// ---- stage a 128x64 bf16 tile into LDS (linear [128][64]), xor-swizzled source ----
__device__ __forceinline__ void stage128x64(const bf16_t* g_base, int k0,
                                            bf16_t* lds, int wid, int lane) {
#pragma unroll
  for (int j = 0; j < 4; ++j) {
    int r0 = (wid * 4 + j) * 8;                 // wave-uniform
    int g_row = r0 + (lane >> 3);
    int g_slot = (lane & 7) ^ (g_row & 7);
    const bf16_t* src = g_base + (size_t)g_row * DIM + k0 + g_slot * 8;
    gload_lds16(src, lds + r0 * 64);
  }
}

// ---------------- fused fp32 -> bf16 converts: X, Wq,Wk,Wv, Wo, Wf ----------------
__global__ __launch_bounds__(256) void cvt_all(const float* __restrict__ X,
                                               const float* __restrict__ Wq,
                                               const float* __restrict__ Wk,
                                               const float* __restrict__ Wv,
                                               const float* __restrict__ Wo,
                                               const float* __restrict__ Wf,
                                               bf16_t* __restrict__ Xb,
                                               bf16_t* __restrict__ W3,
                                               bf16_t* __restrict__ Wob,
                                               bf16_t* __restrict__ Wfb) {
  int i = blockIdx.x * 256 + threadIdx.x;
  const float* src;
  bf16_t* dst;
  int off;
  if (i < 4194304) {
    src = X; dst = Xb; off = i;
  } else {
    int j = i - 4194304;
    if (j < 786432) {
      int seg = j >> 18;
      off = j & 262143;
      src = (seg == 0) ? Wq : ((seg == 1) ? Wk : Wv);
      dst = W3 + (size_t)seg * 1048576;
    } else if (j < 1048576) {
      off = j - 786432; src = Wo; dst = Wob;
    } else {
      off = j - 1048576; src = Wf; dst = Wfb;
    }
  }
  float4 v = reinterpret_cast<const float4*>(src)[off];
  bfv4 o = {(__bf16)v.x, (__bf16)v.y, (__bf16)v.z, (__bf16)v.w};
  reinterpret_cast<bfv4*>(dst)[off] = o;
}

// -------- Q/K/V projection: C = X @ W^T (bf16 out), 2-phase dbuf LDS pipeline --------
// 1-D grid 3072, XCD-aware panel grouping (R14-verified: FETCH 147->90MB).
__global__ __launch_bounds__(256) void gemm_qkv(const bf16_t* __restrict__ A,
                                                const bf16_t* __restrict__ Wall,
                                                bf16_t* __restrict__ Q,
                                                bf16_t* __restrict__ K,
                                                bf16_t* __restrict__ V) {
  __shared__ bf16_t As[2][128 * 64];
  __shared__ bf16_t Bs[2][128 * 64];
  int bid = blockIdx.x;
  int xcd = bid & 7, s = bid >> 3;
  int pair = xcd * 48 + (s >> 3);
  int z = pair >> 7, bx = pair & 127, by = s & 7;
  const bf16_t* Wm = Wall + (size_t)z * (DIM * DIM);
  bf16_t* C = (z == 0) ? Q : ((z == 1) ? K : V);
  int lane = threadIdx.x & 63, wid = threadIdx.x >> 6;
  int lr = lane & 15, lg = lane >> 4;
  int wr = wid >> 1, wc = wid & 1;
  int brow = bx * 128, bcol = by * 128;
  const bf16_t* Ab = A + (size_t)brow * DIM;
  const bf16_t* Bb = Wm + (size_t)bcol * DIM;
  f32x4 acc[4][4] = {};

  stage128x64(Ab, 0, As[0], wid, lane);
  stage128x64(Bb, 0, Bs[0], wid, lane);
  asm volatile("s_waitcnt vmcnt(0)" ::: "memory");
  __builtin_amdgcn_s_barrier();

  auto TILE = [&](const bf16_t* Acur, const bf16_t* Bcur, bf16_t* Anext, bf16_t* Bnext,
                  int knext) __attribute__((always_inline)) {
    if (knext < DIM) {
      stage128x64(Ab, knext, Anext, wid, lane);
      stage128x64(Bb, knext, Bnext, wid, lane);
    }
#pragma unroll
    for (int kk = 0; kk < 2; ++kk) {
      bfv8 af[4], bg[4];
#pragma unroll
      for (int t = 0; t < 4; ++t) {
        int ar = wr * 64 + t * 16 + lr;
        af[t] = *reinterpret_cast<const bfv8*>(&Acur[ar * 64 + (((kk * 4 + lg) ^ (ar & 7)) * 8)]);
        int br = wc * 64 + t * 16 + lr;
        bg[t] = *reinterpret_cast<const bfv8*>(&Bcur[br * 64 + (((kk * 4 + lg) ^ (br & 7)) * 8)]);
      }
#pragma unroll
      for (int i = 0; i < 4; ++i)
#pragma unroll
        for (int j = 0; j < 4; ++j) acc[i][j] = mfma_bf16(af[i], bg[j], acc[i][j]);
    }
    asm volatile("s_waitcnt vmcnt(0)" ::: "memory");
    __builtin_amdgcn_s_barrier();
  };

  for (int ks = 0; ks < DIM / 64; ks += 2) {
    TILE(As[0], Bs[0], As[1], Bs[1], (ks + 1) * 64);
    TILE(As[1], Bs[1], As[0], Bs[0], (ks + 2) * 64);
  }

#pragma unroll
  for (int i = 0; i < 4; ++i) {
    int r = brow + wr * 64 + i * 16 + lg * 4;
#pragma unroll
    for (int j = 0; j < 4; ++j) {
      int c = bcol + wc * 64 + j * 16 + lr;
#pragma unroll
      for (int q = 0; q < 4; ++q) C[(size_t)(r + q) * DIM + c] = (__bf16)acc[i][j][q];
    }
  }
}

// -------- final: d_out = out_pre @ Wo^T (fp32 out), 2-phase dbuf, XCD panel grouping ----
__global__ __launch_bounds__(256) void gemm_final(const bf16_t* __restrict__ A,
                                                  const bf16_t* __restrict__ W,
                                                  float* __restrict__ C) {
  __shared__ bf16_t As[2][128 * 64];
  __shared__ bf16_t Bs[2][128 * 64];
  int bid = blockIdx.x;
  int xcd = bid & 7, s = bid >> 3;
  int bx = xcd * 16 + (s >> 3);
  int by = s & 7;
  int lane = threadIdx.x & 63, wid = threadIdx.x >> 6;
  int lr = lane & 15, lg = lane >> 4;
  int wr = wid >> 1, wc = wid & 1;
  int brow = bx * 128, bcol = by * 128;
  const bf16_t* Ab = A + (size_t)brow * DIM;
  const bf16_t* Bb = W + (size_t)bcol * DIM;
  f32x4 acc[4][4] = {};

  stage128x64(Ab, 0, As[0], wid, lane);
  stage128x64(Bb, 0, Bs[0], wid, lane);
  asm volatile("s_waitcnt vmcnt(0)" ::: "memory");
  __builtin_amdgcn_s_barrier();

  auto TILE = [&](const bf16_t* Acur, const bf16_t* Bcur, bf16_t* Anext, bf16_t* Bnext,
                  int knext) __attribute__((always_inline)) {
    if (knext < DIM) {
      stage128x64(Ab, knext, Anext, wid, lane);
      stage128x64(Bb, knext, Bnext, wid, lane);
    }
#pragma unroll
    for (int kk = 0; kk < 2; ++kk) {
      bfv8 af[4], bg[4];
#pragma unroll
      for (int t = 0; t < 4; ++t) {
        int ar = wr * 64 + t * 16 + lr;
        af[t] = *reinterpret_cast<const bfv8*>(&Acur[ar * 64 + (((kk * 4 + lg) ^ (ar & 7)) * 8)]);
        int br = wc * 64 + t * 16 + lr;
        bg[t] = *reinterpret_cast<const bfv8*>(&Bcur[br * 64 + (((kk * 4 + lg) ^ (br & 7)) * 8)]);
      }
#pragma unroll
      for (int i = 0; i < 4; ++i)
#pragma unroll
        for (int j = 0; j < 4; ++j) acc[i][j] = mfma_bf16(af[i], bg[j], acc[i][j]);
    }
    asm volatile("s_waitcnt vmcnt(0)" ::: "memory");
    __builtin_amdgcn_s_barrier();
  };

  for (int ks = 0; ks < DIM / 64; ks += 2) {
    TILE(As[0], Bs[0], As[1], Bs[1], (ks + 1) * 64);
    TILE(As[1], Bs[1], As[0], Bs[0], (ks + 2) * 64);
  }

#pragma unroll
  for (int i = 0; i < 4; ++i) {
    int r = brow + wr * 64 + i * 16 + lg * 4;
#pragma unroll
    for (int j = 0; j < 4; ++j) {
      int c = bcol + wc * 64 + j * 16 + lr;
#pragma unroll
      for (int q = 0; q < 4; ++q) C[(size_t)(r + q) * DIM + c] = acc[i][j][q];
    }
  }
}

// ------- fused featk+kv v6: in-register kf + per-wave LDS V-transpose; NCHUNK=32 -------
__global__ __launch_bounds__(256, 2) void kv_fused(const bf16_t* __restrict__ Kb,
                                                   const bf16_t* __restrict__ Vb,
                                                   const bf16_t* __restrict__ Wf,
                                                   __half* __restrict__ kv_part) {
  __shared__ bf16_t vt[4][64 * 36];  // per-wave V^T tile [n=64][s=32], stride 36
  int chunk = blockIdx.x, bh = blockIdx.y;
  int b = bh >> 4, h = bh & 15;
  int lane = threadIdx.x & 63, wid = threadIdx.x >> 6;
  int lr = lane & 15, lg = lane >> 4;
  int f0 = wid * 64;
  bfv8 wf[4][2];
#pragma unroll
  for (int ft = 0; ft < 4; ++ft)
#pragma unroll
    for (int kk = 0; kk < 2; ++kk)
      wf[ft][kk] = *reinterpret_cast<const bfv8*>(Wf + (size_t)(f0 + ft * 16 + lr) * HDIM + kk * 32 + lg * 8);
  const bf16_t* Kbase = Kb + (size_t)b * SEQ * DIM + h * HDIM;
  const bf16_t* Vbase = Vb + (size_t)b * SEQ * DIM + h * HDIM;
  int s0 = chunk * (SEQ / NCHUNK);
  bfv8 ones;
#pragma unroll
  for (int j = 0; j < 8; ++j) ones[j] = (lr == 0) ? (__bf16)1.0f : (__bf16)0.0f;

  bfv8 krgA[2][2], krgB[2][2];
#pragma unroll
  for (int st = 0; st < 2; ++st)
#pragma unroll
    for (int kk = 0; kk < 2; ++kk)
      krgA[st][kk] = *reinterpret_cast<const bfv8*>(Kbase + (size_t)(s0 + st * 16 + lr) * DIM + kk * 32 + lg * 8);

  f32x4 acc[4][5] = {};

  auto STEP = [&](int it, bfv8(&krgC)[2][2], bfv8(&krgN)[2][2]) __attribute__((always_inline)) {
    int sb = s0 + it * 32;
    bfv8 vv[4];
#pragma unroll
    for (int rep = 0; rep < 4; ++rep) {
      int idx = rep * 64 + lane;
      vv[rep] = *reinterpret_cast<const bfv8*>(Vbase + (size_t)(sb + (idx >> 3)) * DIM + (idx & 7) * 8);
    }
    if (it + 1 < KV_NIT) {
#pragma unroll
      for (int st = 0; st < 2; ++st)
#pragma unroll
        for (int kk = 0; kk < 2; ++kk)
          krgN[st][kk] = *reinterpret_cast<const bfv8*>(Kbase + (size_t)(sb + 32 + st * 16 + lr) * DIM + kk * 32 + lg * 8);
    }
    f32x4 ckf[2][4] = {};
#pragma unroll
    for (int st = 0; st < 2; ++st)
#pragma unroll
      for (int ft = 0; ft < 4; ++ft)
#pragma unroll
        for (int kk = 0; kk < 2; ++kk) ckf[st][ft] = mfma_bf16(krgC[st][kk], wf[ft][kk], ckf[st][ft]);
#pragma unroll
    for (int rep = 0; rep < 4; ++rep) {
      int idx = rep * 64 + lane;
#pragma unroll
      for (int j = 0; j < 8; ++j) vt[wid][((idx & 7) * 8 + j) * 36 + (idx >> 3)] = vv[rep][j];
    }
    bfv8 af[4];
#pragma unroll
    for (int ft = 0; ft < 4; ++ft)
#pragma unroll
      for (int st = 0; st < 2; ++st)
#pragma unroll
        for (int q = 0; q < 4; ++q) {
          float x = ckf[st][ft][q];
          x = (x > 0.0f) ? (x + 1.0f) : __expf(x);
          af[ft][st * 4 + q] = (__bf16)x;
        }
    bfv8 bg[4];
#pragma unroll
    for (int nt = 0; nt < 4; ++nt) {
      bfv4 lo = *reinterpret_cast<const bfv4*>(&vt[wid][(nt * 16 + lr) * 36 + lg * 4]);
      bfv4 hi = *reinterpret_cast<const bfv4*>(&vt[wid][(nt * 16 + lr) * 36 + 16 + lg * 4]);
#pragma unroll
      for (int e = 0; e < 4; ++e) { bg[nt][e] = lo[e]; bg[nt][4 + e] = hi[e]; }
    }
#pragma unroll
    for (int ft = 0; ft < 4; ++ft) {
#pragma unroll
      for (int nt = 0; nt < 4; ++nt) acc[ft][nt] = mfma_bf16(af[ft], bg[nt], acc[ft][nt]);
      acc[ft][4] = mfma_bf16(af[ft], ones, acc[ft][4]);
    }
  };

  for (int it2 = 0; it2 < KV_NIT; it2 += 2) {
    STEP(it2, krgA, krgB);
    STEP(it2 + 1, krgB, krgA);
  }

  __half* outb = kv_part + ((size_t)chunk * 32 + bh) * (FDIM * 68);
#pragma unroll
  for (int ft = 0; ft < 4; ++ft)
#pragma unroll
    for (int q = 0; q < 4; ++q) {
      int f = f0 + ft * 16 + lg * 4 + q;
#pragma unroll
      for (int nt = 0; nt < 4; ++nt)
        outb[(size_t)f * 68 + nt * 16 + lr] = __float2half(acc[ft][nt][q]);
      if (lr < 4) outb[(size_t)f * 68 + 64 + lr] = __float2half(acc[ft][4][q]);
    }
}

// ------- reduce NCHUNK fp16 partials [bh][f][n] -> kvT bf16 [bh][n=80][f-XOR-swz] -------
__global__ __launch_bounds__(256) void kv_reduce(const __half* __restrict__ part,
                                                 bf16_t* __restrict__ kvT) {
  int i = blockIdx.x * 256 + threadIdx.x;  // grid 2560: 557056 reduce + 98304 zero-fill
  if (i < KVP_CH) {
    int n = i % 68;
    int t = i / 68;  // bh*256 + f
    int f = t & 255, bh = t >> 8;
    float s = 0.0f;
#pragma unroll
    for (int c = 0; c < NCHUNK; ++c) s += __half2float(part[(size_t)c * KVP_CH + i]);
    int fs = ((((f >> 3) ^ (n & 7)) << 3) | (f & 7));
    kvT[((size_t)bh * 80 + n) * FDIM + fs] = (__bf16)s;
  } else {
    int j = i - KVP_CH;  // 32*12*256
    int f = j & 255;
    int t = j >> 8;
    int n = 68 + t % 12, bh = t / 12;
    kvT[((size_t)bh * 80 + n) * FDIM + f] = (__bf16)0.0f;
  }
}

// ------- fused featq+readout, 128 rows/block: stage kvT once, two 64-row sub-tiles ------
// grid (M/128, NH); b = row00>>13 (128-row blocks never straddle batch boundary).
__global__ __launch_bounds__(256) void attn_fused(const bf16_t* __restrict__ Qb,
                                                  const bf16_t* __restrict__ Wf,
                                                  const bf16_t* __restrict__ kvT,
                                                  bf16_t* __restrict__ outp) {
  __shared__ bf16_t qf_lds[64 * 264];
  __shared__ bf16_t kv_lds[80 * 256];
  int rb = blockIdx.x, h = blockIdx.y;
  int row00 = rb * 128;
  int bh = (row00 >> 13) * NH + h;
  int lane = threadIdx.x & 63, wid = threadIdx.x >> 6;
  int lr = lane & 15, lg = lane >> 4;
  int f0 = wid * 64;
  // stage kvT[bh] -> LDS once (linear; swizzle pre-applied in global layout)
  const bf16_t* kvTb = kvT + (size_t)bh * 80 * FDIM;
#pragma unroll
  for (int i = 0; i < 10; ++i) {
    int sbase = wid * 640 + i * 64;
    gload_lds16(kvTb + (size_t)(sbase + lane) * 8, kv_lds + sbase * 8);
  }
  bfv8 wfb[4][2];
#pragma unroll
  for (int t = 0; t < 4; ++t)
#pragma unroll
    for (int kk = 0; kk < 2; ++kk)
      wfb[t][kk] = *reinterpret_cast<const bfv8*>(Wf + (size_t)(f0 + t * 16 + lr) * HDIM + kk * 32 + lg * 8);

#pragma unroll
  for (int sub = 0; sub < 2; ++sub) {
    int row0 = row00 + sub * 64;
    bfv8 qa[4][2];
#pragma unroll
    for (int t = 0; t < 4; ++t)
#pragma unroll
      for (int kk = 0; kk < 2; ++kk)
        qa[t][kk] = *reinterpret_cast<const bfv8*>(Qb + (size_t)(row0 + t * 16 + lr) * DIM + h * HDIM + kk * 32 + lg * 8);
    f32x4 cq[4][4] = {};
#pragma unroll
    for (int rt = 0; rt < 4; ++rt)
#pragma unroll
      for (int ft = 0; ft < 4; ++ft)
#pragma unroll
        for (int kk = 0; kk < 2; ++kk) cq[rt][ft] = mfma_bf16(qa[rt][kk], wfb[ft][kk], cq[rt][ft]);
#pragma unroll
    for (int rt = 0; rt < 4; ++rt)
#pragma unroll
      for (int ft = 0; ft < 4; ++ft)
#pragma unroll
        for (int q = 0; q < 4; ++q) {
          float x = cq[rt][ft][q];
          x = (x > 0.0f) ? (x + 1.0f) : __expf(x);
          qf_lds[(size_t)(rt * 16 + lg * 4 + q) * 264 + f0 + ft * 16 + lr] = (__bf16)x;
        }
    __syncthreads();  // qf visible (sub0 also drains kv staging vmcnt)
    f32x4 acc[5] = {};
#pragma unroll
    for (int ks = 0; ks < 8; ++ks) {
      bfv8 a = *reinterpret_cast<const bfv8*>(&qf_lds[(size_t)(wid * 16 + lr) * 264 + ks * 32 + lg * 8]);
#pragma unroll
      for (int nt = 0; nt < 5; ++nt) {
        bfv8 bg = *reinterpret_cast<const bfv8*>(
            &kv_lds[(size_t)(nt * 16 + lr) * 256 + (((ks * 4 + lg) ^ (lr & 7)) * 8)]);
        acc[nt] = mfma_bf16(a, bg, acc[nt]);
      }
    }
    __syncthreads();  // all waves done reading qf_lds
#pragma unroll
    for (int q = 0; q < 4; ++q) {
      float nrm = __shfl(acc[4][q], (lane & 48)) + 1e-6f;
      int row = wid * 16 + lg * 4 + q;
#pragma unroll
      for (int nt = 0; nt < 4; ++nt)
        qf_lds[(size_t)row * 264 + nt * 16 + lr] = (__bf16)(acc[nt][q] / nrm);
    }
    __syncthreads();
#pragma unroll
    for (int rep = 0; rep < 2; ++rep) {
      int id = rep * 256 + threadIdx.x;
      int row = id >> 3, c8 = id & 7;
      bfv8 v = *reinterpret_cast<const bfv8*>(&qf_lds[(size_t)row * 264 + c8 * 8]);
      *reinterpret_cast<bfv8*>(&outp[(size_t)(row0 + row) * DIM + h * HDIM + c8 * 8]) = v;
    }
    __syncthreads();  // out-tile reads done before sub1 overwrites qf_lds
  }
}

extern "C" void kernel_launch(void* const* d_in, const int* in_sizes, int n_in,
                              void* d_out, int out_size, void* d_ws, size_t ws_size,
                              hipStream_t stream) {
  const float* X  = (const float*)d_in[0];
  const float* Wq = (const float*)d_in[1];
  const float* Wk = (const float*)d_in[2];
  const float* Wv = (const float*)d_in[3];
  const float* Wo = (const float*)d_in[4];
  const float* Wf = (const float*)d_in[5];
  float* out = (float*)d_out;
  char* ws = (char*)d_ws;
  const size_t MB = 1ull << 20;
  if (ws_size < 75 * MB) return;

  // arena (75 MB) + d_out (64 MB) as scratch for K/V
  bf16_t* Xb  = (bf16_t*)(ws + 0 * MB);    // 32MB; dead after gemm_qkv
  bf16_t* W3  = (bf16_t*)(ws + 32 * MB);   // 6MB;  dead after gemm_qkv
  bf16_t* Qb  = (bf16_t*)(ws + 38 * MB);   // 32MB; live until attn_fused
  bf16_t* Wob = (bf16_t*)(ws + 70 * MB);   // 2MB;  live until gemm_final
  bf16_t* Wfb = (bf16_t*)(ws + 72 * MB);   // 32KB
  bf16_t* kvT = (bf16_t*)(ws + 73 * MB);   // 1.31MB
  __half* kv_part = (__half*)(ws + 0 * MB);  // 35.7MB fp16 over dead Xb+W3
  bf16_t* outp = (bf16_t*)(ws + 0 * MB);   // 32MB over dead kv_part
  bf16_t* Kb = (bf16_t*)d_out;             // 32MB scratch in d_out
  bf16_t* Vb = Kb + (size_t)MROWS * DIM;   // 32MB scratch in d_out

  cvt_all<<<20496, 256, 0, stream>>>(X, Wq, Wk, Wv, Wo, Wf, Xb, W3, Wob, Wfb);

  gemm_qkv<<<3072, 256, 0, stream>>>(Xb, W3, Qb, Kb, Vb);
  kv_fused<<<dim3(NCHUNK, 32), 256, 0, stream>>>(Kb, Vb, Wfb, kv_part);
  kv_reduce<<<2560, 256, 0, stream>>>(kv_part, kvT);
  attn_fused<<<dim3(128, NH), 256, 0, stream>>>(Qb, Wfb, kvT, outp);
  gemm_final<<<1024, 256, 0, stream>>>(outp, Wob, out);
}